// Round 11
// baseline (657.422 us; speedup 1.0000x reference)
//
#include <hip/hip_runtime.h>
#include <hip/hip_bf16.h>
#include <math.h>

#define NN 16000
#define NPAD 16128
#define NE 256000
#define H 192
#define NL 4
#define NBATCH 8
#define VEt 8
#define HH (H*H)
#define EML 16   // edges per wave in k_edgemlp

typedef __hip_bfloat16 bf16;
typedef unsigned short u16;
typedef unsigned char u8;
typedef __attribute__((ext_vector_type(8))) short bfrag_t;
typedef __attribute__((ext_vector_type(4))) float facc_t;

__device__ __forceinline__ bf16 f2b(float v){ return __float2bfloat16(v); }
__device__ __forceinline__ float b2f(u16 v){ bf16 h; *(u16*)&h = v; return __bfloat162float(h); }

// ---- fp8 e4m3fn (OCP) software encode, RTNE ----
__device__ __forceinline__ unsigned enc8(float x){
    unsigned u = __float_as_uint(x);
    unsigned s = (u >> 24) & 0x80u;
    float ax = fabsf(x);
    if(ax >= 448.f) return s | 0x7Eu;
    if(ax < 0.015625f){                      // < 2^-6: subnormal, step 2^-9
        int q = (int)rintf(ax * 512.f);      // 0..8 (8 rolls into exp=1 correctly)
        return s | (unsigned)q;
    }
    unsigned au = u & 0x7FFFFFFFu;
    unsigned lsb = (au >> 20) & 1u;
    au += 0x7FFFFu + lsb;                    // RTNE to 3 mantissa bits
    unsigned E = (au >> 23) - 127u;
    unsigned M = (au >> 20) & 7u;
    if((int)E > 8) return s | 0x7Eu;
    return s | ((E + 7u) << 3) | M;
}
// ---- fp8 e4m3fn decode (HW if available) ----
__device__ __forceinline__ float dec8(unsigned v){
#if __has_builtin(__builtin_amdgcn_cvt_f32_fp8)
    return __builtin_amdgcn_cvt_f32_fp8((int)v, 0);
#else
    unsigned e = (v >> 3) & 15u, m = v & 7u;
    float mag = e ? __builtin_ldexpf((float)(8u + m), (int)e - 10)
                  : __builtin_ldexpf((float)m, -9);
    return (v & 0x80u) ? -mag : mag;
#endif
}

__global__ void k_sentinel(float* __restrict__ out, float v){ out[0] = v; }

// ---------------- transpose 18 H×H fp32 weight mats into bf16 [n][k] ----------------
__global__ void k_transpose(const float* __restrict__ wq, const float* __restrict__ wk,
                            const float* __restrict__ wv, const float* __restrict__ wsk,
                            const float* __restrict__ w1, u16* __restrict__ wt){
    int mat = blockIdx.x;
    const float* src;
    if(mat < 4)       src = wq  + (size_t)mat*HH;
    else if(mat < 8)  src = wk  + (size_t)(mat-4)*HH;
    else if(mat < 12) src = wv  + (size_t)(mat-8)*HH;
    else if(mat < 16) src = wsk + (size_t)(mat-12)*HH;
    else              src = w1  + (size_t)(mat-16)*HH;
    u16* dst = wt + (size_t)mat*HH;
    const int slice = HH/8;
    int base = blockIdx.y*slice;
    for(int i = base + threadIdx.x; i < base + slice; i += blockDim.x){
        int k = i / H, n = i % H;
        bf16 b = f2b(src[i]);
        dst[n*H + k] = *(u16*)&b;
    }
}

// ---------------- time embedding MLP ----------------
__global__ void k_tvec(const int* __restrict__ tg, const float* __restrict__ w1,
                       const float* __restrict__ b1, const float* __restrict__ w2,
                       const float* __restrict__ b2, float* __restrict__ tvec){
    int b = blockIdx.x, j = threadIdx.x;
    __shared__ float emb[H], h1[H];
    float t = (float)tg[b];
    if(j < 96){
        float fr = __expf(-logf(10000.0f) * (float)j / 96.0f);
        float ang = t * fr;
        emb[j]      = sinf(ang);
        emb[j + 96] = cosf(ang);
    }
    __syncthreads();
    float acc = b1[j];
    for(int k = 0; k < H; k++) acc += emb[k] * w1[k*H + j];
    h1[j] = acc / (1.f + __expf(-acc));
    __syncthreads();
    float acc2 = b2[j];
    for(int k = 0; k < H; k++) acc2 += h1[k] * w2[k*H + j];
    tvec[b*H + j] = acc2;
}

// ---------------- x0 ----------------
__global__ void k_init_x(const float* __restrict__ nemb, const float* __restrict__ memb,
                         const float* __restrict__ tvec, const int* __restrict__ ntype,
                         const int* __restrict__ emask, const int* __restrict__ nbatch,
                         float* __restrict__ x, u16* __restrict__ xb){
    int idx = blockIdx.x*blockDim.x + threadIdx.x;
    if(idx >= NN*H) return;
    int n = idx / H, c = idx % H;
    float v = nemb[(size_t)ntype[n]*H + c] + tvec[nbatch[n]*H + c]
            + memb[(size_t)emask[n]*H + c];
    x[idx] = v;
    bf16 b = f2b(v); xb[idx] = *(u16*)&b;
}

// ---------------- counting sort of edges by dst ----------------
__global__ void k_zero_i(int* __restrict__ p, int n){
    int i = blockIdx.x*blockDim.x + threadIdx.x;
    if(i < n) p[i] = 0;
}
__global__ void k_count(const int* __restrict__ edst, int* __restrict__ cnt){
    int e = blockIdx.x*blockDim.x + threadIdx.x;
    if(e < NE) atomicAdd(&cnt[edst[e]], 1);
}
__global__ __launch_bounds__(1024) void k_scan(const int* __restrict__ cnt,
                                               int* __restrict__ ofs, int* __restrict__ cur){
    __shared__ int wsum[16];
    __shared__ int carry_s;
    int tid = threadIdx.x, lane = tid & 63, w = tid >> 6;
    if(tid == 0) carry_s = 0;
    __syncthreads();
    for(int base = 0; base < NN; base += 1024){
        int idx = base + tid;
        int v = (idx < NN) ? cnt[idx] : 0;
        int sc = v;
        #pragma unroll
        for(int o = 1; o < 64; o <<= 1){
            int t = __shfl_up(sc, o);
            if(lane >= o) sc += t;
        }
        if(lane == 63) wsum[w] = sc;
        __syncthreads();
        if(w == 0){
            int ws = (lane < 16) ? wsum[lane] : 0;
            #pragma unroll
            for(int o = 1; o < 16; o <<= 1){
                int t = __shfl_up(ws, o);
                if(lane >= o) ws += t;
            }
            if(lane < 16) wsum[lane] = ws;
        }
        __syncthreads();
        int wbase = (w > 0) ? wsum[w-1] : 0;
        int c = carry_s;
        int excl = c + wbase + sc - v;
        if(idx < NN){ ofs[idx] = excl; cur[idx] = excl; }
        __syncthreads();
        if(tid == 0) carry_s = c + wsum[15];
        __syncthreads();
    }
    if(threadIdx.x == 0) ofs[NN] = carry_s;
}
__global__ void k_scatter(const int* __restrict__ esrc, const int* __restrict__ edst,
                          const int* __restrict__ etype, const int* __restrict__ nbatch,
                          int* __restrict__ cur, int* __restrict__ ssrc, int* __restrict__ seix){
    int e = blockIdx.x*blockDim.x + threadIdx.x;
    if(e >= NE) return;
    int s = esrc[e], d = edst[e];
    int pos = atomicAdd(&cur[d], 1);
    ssrc[pos] = s;
    seix[pos] = nbatch[s]*VEt + etype[e];
}

// ---------------- e-tables ----------------
__global__ void k_etab(const float* __restrict__ eemb, const float* __restrict__ tvec,
                       const float* __restrict__ we, float* __restrict__ etab){
    int blk = blockIdx.x;
    int l = blk >> 6, idx = blk & 63, b = idx >> 3, et = idx & 7;
    int c = threadIdx.x;
    __shared__ float a[H];
    a[c] = eemb[et*H + c] + tvec[b*H + c];
    __syncthreads();
    float acc = 0.f;
    const float* w = we + (size_t)l*HH;
    for(int k = 0; k < H; k++) acc += a[k] * w[k*H + c];
    etab[(size_t)blk*H + c] = acc;
}

// ---------------- c-table ----------------
__global__ void k_ctab(const float* __restrict__ eemb, const float* __restrict__ tvec,
                       const float* __restrict__ w1, const float* __restrict__ b1,
                       float* __restrict__ ctab){
    int idx = blockIdx.x, b = idx >> 3, et = idx & 7;
    int c = threadIdx.x;
    __shared__ float a[H];
    a[c] = eemb[et*H + c] + tvec[b*H + c];
    __syncthreads();
    float acc = b1[c];
    for(int k = 0; k < H; k++){
        acc += a[k]          * w1[(size_t)(2*H + k)*H + c];
        acc += tvec[b*H + k] * w1[(size_t)(3*H + k)*H + c];
    }
    ctab[(size_t)idx*H + c] = acc;
}

// ---------------- MFMA GEMM; obf: 0=fp32 out, 2=fp8 out ----------------
struct GemmP {
    const u16* wt[4];
    const float* bias[4];
    void* out[4];
    int obf[4];
};
__global__ __launch_bounds__(256) void k_gemm(const u16* __restrict__ A, GemmP P){
    int oi = blockIdx.y / 3, nt = blockIdx.y % 3;
    const u16* Wt = P.wt[oi];
    const float* bias = P.bias[oi];
    int wave = threadIdx.x >> 6, lane = threadIdx.x & 63;
    int quad = lane >> 4, l16 = lane & 15;
    int m0 = blockIdx.x*256 + wave*64;
    int n0 = nt*64;
    facc_t acc[4][4];
    #pragma unroll
    for(int i = 0; i < 4; i++)
        #pragma unroll
        for(int j = 0; j < 4; j++){ acc[i][j][0]=0.f; acc[i][j][1]=0.f; acc[i][j][2]=0.f; acc[i][j][3]=0.f; }
    #pragma unroll
    for(int kc = 0; kc < 6; kc++){
        int kb = kc*32 + quad*8;
        bfrag_t af[4], bg[4];
        #pragma unroll
        for(int i = 0; i < 4; i++) af[i] = *(const bfrag_t*)(A  + (size_t)(m0 + i*16 + l16)*H + kb);
        #pragma unroll
        for(int j = 0; j < 4; j++) bg[j] = *(const bfrag_t*)(Wt + (size_t)(n0 + j*16 + l16)*H + kb);
        #pragma unroll
        for(int i = 0; i < 4; i++)
            #pragma unroll
            for(int j = 0; j < 4; j++)
                acc[i][j] = __builtin_amdgcn_mfma_f32_16x16x32_bf16(af[i], bg[j], acc[i][j], 0, 0, 0);
    }
    float bv[4];
    #pragma unroll
    for(int j = 0; j < 4; j++) bv[j] = bias ? bias[n0 + j*16 + l16] : 0.f;
    if(P.obf[oi] == 2){
        u8* out = (u8*)P.out[oi];
        #pragma unroll
        for(int i = 0; i < 4; i++){
            int rb = m0 + i*16 + quad*4;
            #pragma unroll
            for(int r = 0; r < 4; r++){
                int row = rb + r;
                if(row < NN){
                    #pragma unroll
                    for(int j = 0; j < 4; j++)
                        out[(size_t)row*H + n0 + j*16 + l16] = (u8)enc8(acc[i][j][r] + bv[j]);
                }
            }
        }
    } else {
        float* out = (float*)P.out[oi];
        #pragma unroll
        for(int i = 0; i < 4; i++){
            int rb = m0 + i*16 + quad*4;
            #pragma unroll
            for(int r = 0; r < 4; r++){
                int row = rb + r;
                if(row < NN){
                    #pragma unroll
                    for(int j = 0; j < 4; j++)
                        out[(size_t)row*H + n0 + j*16 + l16] = acc[i][j][r] + bv[j];
                }
            }
        }
    }
}

// ---------------- fused attention + gate + LN, one wave/node, dual-stream, fp8 K/V ----------------
__global__ __launch_bounds__(256) void k_attn(
    const float* __restrict__ Q, const u8* __restrict__ Kb,
    const u8* __restrict__ Vb, const float* __restrict__ XR,
    const float* __restrict__ etab, const int* __restrict__ ofs,
    const int* __restrict__ ssrc, const int* __restrict__ seix,
    const float* __restrict__ wb, const float* __restrict__ lng, const float* __restrict__ lnb,
    float* __restrict__ x, u16* __restrict__ xb)
{
    int n = blockIdx.x*4 + (threadIdx.x >> 6);
    int lane = threadIdx.x & 63;
    int ch = lane*3;
    size_t base = (size_t)n*H + ch;
    const float scale = 0.14433756729740646f;   // 1/sqrt(48)
    float q0 = Q[base], q1 = Q[base+1], q2 = Q[base+2];
    int p0 = ofs[n], p1 = ofs[n+1];
    float mA = -3.0e38f, lA = 0.f, aA0 = 0.f, aA1 = 0.f, aA2 = 0.f;
    float mB = -3.0e38f, lB = 0.f, aB0 = 0.f, aB1 = 0.f, aB2 = 0.f;
    int p = p0;
    for(; p + 1 < p1; p += 2){
        int sA = ssrc[p],   eiA = seix[p];
        int sB = ssrc[p+1], eiB = seix[p+1];
        const u8*    kpA = Kb   + (size_t)sA*H  + ch;
        const float* epA = etab + (size_t)eiA*H + ch;
        const u8*    kpB = Kb   + (size_t)sB*H  + ch;
        const float* epB = etab + (size_t)eiB*H + ch;
        float eA0 = epA[0], eA1 = epA[1], eA2 = epA[2];
        float eB0 = epB[0], eB1 = epB[1], eB2 = epB[2];
        float tA = q0*(dec8(kpA[0])+eA0) + q1*(dec8(kpA[1])+eA1) + q2*(dec8(kpA[2])+eA2);
        float tB = q0*(dec8(kpB[0])+eB0) + q1*(dec8(kpB[1])+eB1) + q2*(dec8(kpB[2])+eB2);
        tA += __shfl_xor(tA,1); tB += __shfl_xor(tB,1);
        tA += __shfl_xor(tA,2); tB += __shfl_xor(tB,2);
        tA += __shfl_xor(tA,4); tB += __shfl_xor(tB,4);
        tA += __shfl_xor(tA,8); tB += __shfl_xor(tB,8);
        float scA = tA*scale, scB = tB*scale;
        const u8* vpA = Vb + (size_t)sA*H + ch;
        const u8* vpB = Vb + (size_t)sB*H + ch;
        {
            float mn = fmaxf(mA, scA);
            float corr = __expf(mA - mn), pw = __expf(scA - mn);
            lA  = lA*corr + pw;
            aA0 = aA0*corr + pw*(dec8(vpA[0])+eA0);
            aA1 = aA1*corr + pw*(dec8(vpA[1])+eA1);
            aA2 = aA2*corr + pw*(dec8(vpA[2])+eA2);
            mA = mn;
        }
        {
            float mn = fmaxf(mB, scB);
            float corr = __expf(mB - mn), pw = __expf(scB - mn);
            lB  = lB*corr + pw;
            aB0 = aB0*corr + pw*(dec8(vpB[0])+eB0);
            aB1 = aB1*corr + pw*(dec8(vpB[1])+eB1);
            aB2 = aB2*corr + pw*(dec8(vpB[2])+eB2);
            mB = mn;
        }
    }
    if(p < p1){
        int sA = ssrc[p], eiA = seix[p];
        const u8*    kpA = Kb   + (size_t)sA*H  + ch;
        const float* epA = etab + (size_t)eiA*H + ch;
        float eA0 = epA[0], eA1 = epA[1], eA2 = epA[2];
        float tA = q0*(dec8(kpA[0])+eA0) + q1*(dec8(kpA[1])+eA1) + q2*(dec8(kpA[2])+eA2);
        tA += __shfl_xor(tA,1); tA += __shfl_xor(tA,2); tA += __shfl_xor(tA,4); tA += __shfl_xor(tA,8);
        float scA = tA*scale;
        const u8* vpA = Vb + (size_t)sA*H + ch;
        float mn = fmaxf(mA, scA);
        float corr = __expf(mA - mn), pw = __expf(scA - mn);
        lA  = lA*corr + pw;
        aA0 = aA0*corr + pw*(dec8(vpA[0])+eA0);
        aA1 = aA1*corr + pw*(dec8(vpA[1])+eA1);
        aA2 = aA2*corr + pw*(dec8(vpA[2])+eA2);
        mA = mn;
    }
    float mF = fmaxf(mA, mB);
    float cA = __expf(mA - mF), cB = __expf(mB - mF);
    float l  = lA*cA + lB*cB;
    float a0 = aA0*cA + aB0*cB;
    float a1 = aA1*cA + aB1*cB;
    float a2 = aA2*cA + aB2*cB;
    float inv = (p1 > p0) ? 1.f/l : 0.f;
    float o0 = a0*inv, o1 = a1*inv, o2 = a2*inv;
    float xr0 = XR[base], xr1 = XR[base+1], xr2 = XR[base+2];
    float sd = o0*wb[ch]  + o1*wb[ch+1]  + o2*wb[ch+2]
             + xr0*wb[H+ch] + xr1*wb[H+ch+1] + xr2*wb[H+ch+2]
             + (o0-xr0)*wb[2*H+ch] + (o1-xr1)*wb[2*H+ch+1] + (o2-xr2)*wb[2*H+ch+2];
    sd += __shfl_xor(sd,1); sd += __shfl_xor(sd,2); sd += __shfl_xor(sd,4);
    sd += __shfl_xor(sd,8); sd += __shfl_xor(sd,16); sd += __shfl_xor(sd,32);
    float beta = 1.f/(1.f + __expf(-sd));
    float h0 = beta*xr0 + (1.f-beta)*o0;
    float h1 = beta*xr1 + (1.f-beta)*o1;
    float h2 = beta*xr2 + (1.f-beta)*o2;
    float y0 = x[base] + h0, y1 = x[base+1] + h1, y2 = x[base+2] + h2;
    float s3 = y0 + y1 + y2;
    s3 += __shfl_xor(s3,1); s3 += __shfl_xor(s3,2); s3 += __shfl_xor(s3,4);
    s3 += __shfl_xor(s3,8); s3 += __shfl_xor(s3,16); s3 += __shfl_xor(s3,32);
    float mean = s3 * (1.f/H);
    float d0 = y0-mean, d1 = y1-mean, d2 = y2-mean;
    float v3 = d0*d0 + d1*d1 + d2*d2;
    v3 += __shfl_xor(v3,1); v3 += __shfl_xor(v3,2); v3 += __shfl_xor(v3,4);
    v3 += __shfl_xor(v3,8); v3 += __shfl_xor(v3,16); v3 += __shfl_xor(v3,32);
    float rs = rsqrtf(v3*(1.f/H) + 1e-5f);
    float z0 = d0*rs*lng[ch]   + lnb[ch];
    float z1 = d1*rs*lng[ch+1] + lnb[ch+1];
    float z2 = d2*rs*lng[ch+2] + lnb[ch+2];
    x[base] = z0; x[base+1] = z1; x[base+2] = z2;
    bf16 t0 = f2b(z0), t1 = f2b(z1), t2 = f2b(z2);
    xb[base] = *(u16*)&t0; xb[base+1] = *(u16*)&t1; xb[base+2] = *(u16*)&t2;
}

// ---------------- node logits ----------------
__global__ void k_nodeout(const float* __restrict__ x, const float* __restrict__ w,
                          const float* __restrict__ b, float* __restrict__ out){
    int j = threadIdx.x & 31;
    int n = blockIdx.x*8 + (threadIdx.x >> 5);
    float acc = b[j];
    const float* xr = x + (size_t)n*H;
    for(int k = 0; k < H; k++) acc += xr[k] * w[k*32 + j];
    out[(size_t)n*32 + j] = acc;
}

// ---------------- edge logits: fp8 gathers, 16 edges/wave, split-butterfly ----------------
__global__ __launch_bounds__(256) void k_edgemlp(
    const int* __restrict__ esrc, const int* __restrict__ edst, const int* __restrict__ etype,
    const int* __restrict__ nb,
    const u8* __restrict__ xs1, const u8* __restrict__ xd1, const float* __restrict__ ctab,
    const float* __restrict__ w2, const float* __restrict__ b2p, float* __restrict__ out)
{
    int wid = blockIdx.x*4 + (threadIdx.x >> 6);
    int lane = threadIdx.x & 63;
    int ch = lane*3;
    float w2r[3][8];
    #pragma unroll
    for(int t = 0; t < 3; t++)
        #pragma unroll
        for(int j = 0; j < 8; j++) w2r[t][j] = w2[(ch+t)*8 + j];
    int jout = (lane&1)*4 + (lane&2) + ((lane&4)>>2);
    float bo = (lane < 8) ? b2p[jout] : 0.f;
    int b0 = lane & 1, b1 = lane & 2, b2m = lane & 4;
    int e0 = wid*EML;
    for(int e = e0; e < e0 + EML; e++){
        int s = esrc[e], d = edst[e];
        int ct = nb[s]*VEt + etype[e];
        const u8*    ap = xs1 + (size_t)s*H + ch;
        const u8*    bp = xd1 + (size_t)d*H + ch;
        const float* cp = ctab + (size_t)ct*H + ch;
        float h0, h1, h2;
        { float v = dec8(ap[0])+dec8(bp[0])+cp[0]; h0 = v/(1.f+__expf(-v)); }
        { float v = dec8(ap[1])+dec8(bp[1])+cp[1]; h1 = v/(1.f+__expf(-v)); }
        { float v = dec8(ap[2])+dec8(bp[2])+cp[2]; h2 = v/(1.f+__expf(-v)); }
        float pj[8];
        #pragma unroll
        for(int j = 0; j < 8; j++)
            pj[j] = h0*w2r[0][j] + h1*w2r[1][j] + h2*w2r[2][j];
        float v4[4];
        #pragma unroll
        for(int t = 0; t < 4; t++){
            float send = b0 ? pj[t] : pj[t+4];
            float keep = b0 ? pj[t+4] : pj[t];
            v4[t] = keep + __shfl_xor(send, 1);
        }
        float v2[2];
        #pragma unroll
        for(int t = 0; t < 2; t++){
            float send = b1 ? v4[t] : v4[t+2];
            float keep = b1 ? v4[t+2] : v4[t];
            v2[t] = keep + __shfl_xor(send, 2);
        }
        float v1;
        {
            float send = b2m ? v2[0] : v2[1];
            float keep = b2m ? v2[1] : v2[0];
            v1 = keep + __shfl_xor(send, 4);
        }
        v1 += __shfl_xor(v1, 8); v1 += __shfl_xor(v1, 16); v1 += __shfl_xor(v1, 32);
        if(lane < 8) out[(size_t)e*8 + jout] = v1 + bo;
    }
}

extern "C" void kernel_launch(void* const* d_in, const int* in_sizes, int n_in,
                              void* d_out, int out_size, void* d_ws, size_t ws_size,
                              hipStream_t stream)
{
    {
        int bad = -1;
        if(n_in != 31) bad = 100;
        else {
            const int chk_idx[9] = {0, 7, 16, 21, 23, 26, 27, 29, 30};
            const int chk_sz [9] = {32*H, NL*HH, NL*3*H, 4*HH, H*8, NE, 2*NE, NN, NBATCH};
            for(int i = 0; i < 9; i++) if(in_sizes[chk_idx[i]] != chk_sz[i]){ bad = chk_idx[i]; break; }
        }
        if(bad >= 0){ k_sentinel<<<1,1,0,stream>>>((float*)d_out, 20000.f + 256.f*bad); return; }
        if(out_size != NN*32 + NE*8){ k_sentinel<<<1,1,0,stream>>>((float*)d_out, 30000.f); return; }
    }

    const float* node_emb = (const float*)d_in[0];
    const float* edge_emb = (const float*)d_in[1];
    const float* time_w1  = (const float*)d_in[2];
    const float* time_b1  = (const float*)d_in[3];
    const float* time_w2  = (const float*)d_in[4];
    const float* time_b2  = (const float*)d_in[5];
    const float* mask_emb = (const float*)d_in[6];
    const float* wq       = (const float*)d_in[7];
    const float* bq       = (const float*)d_in[8];
    const float* wk       = (const float*)d_in[9];
    const float* bk       = (const float*)d_in[10];
    const float* wv       = (const float*)d_in[11];
    const float* bv       = (const float*)d_in[12];
    const float* we       = (const float*)d_in[13];
    const float* wskip    = (const float*)d_in[14];
    const float* bskip    = (const float*)d_in[15];
    const float* wbeta    = (const float*)d_in[16];
    const float* ln_g     = (const float*)d_in[17];
    const float* ln_b     = (const float*)d_in[18];
    const float* now      = (const float*)d_in[19];
    const float* nob      = (const float*)d_in[20];
    const float* ew1      = (const float*)d_in[21];
    const float* eb1      = (const float*)d_in[22];
    const float* ew2      = (const float*)d_in[23];
    const float* eb2      = (const float*)d_in[24];
    const int* node_type  = (const int*)d_in[25];
    const int* edge_type  = (const int*)d_in[26];
    const int* edge_index = (const int*)d_in[27];
    const int* edit_mask  = (const int*)d_in[28];
    const int* node_batch = (const int*)d_in[29];
    const int* t_graph    = (const int*)d_in[30];
    const int* esrc = edge_index;
    const int* edst = edge_index + NE;

    char* wsb = (char*)d_ws;
    size_t off = 0;
    auto take = [&](size_t bytes) -> char* {
        char* r = wsb + off;
        off += (bytes + 255) & ~(size_t)255;
        return r;
    };
    float* tvec = (float*)take((size_t)NBATCH*H*4);
    float* x    = (float*)take((size_t)NN*H*4);
    u16*   xb   = (u16*)  take((size_t)NPAD*H*2);
    float* Q    = (float*)take((size_t)NN*H*4);
    u8*    Kb   = (u8*)   take((size_t)NN*H);
    u8*    Vb   = (u8*)   take((size_t)NN*H);
    float* XR   = (float*)take((size_t)NN*H*4);
    u8*    xs1  = (u8*)   take((size_t)NN*H);
    u8*    xd1  = (u8*)   take((size_t)NN*H);
    float* etab = (float*)take((size_t)NL*64*H*4);
    float* ctab = (float*)take((size_t)64*H*4);
    u16*   wt   = (u16*)  take((size_t)18*HH*2);
    int* cnt    = (int*)  take((size_t)(NN+1)*4);
    int* offa   = (int*)  take((size_t)(NN+1)*4);
    int* cur    = (int*)  take((size_t)(NN+1)*4);
    int* ssrc   = (int*)  take((size_t)NE*4);
    int* seix   = (int*)  take((size_t)NE*4);

    if(ws_size < off){
        k_sentinel<<<1,1,0,stream>>>((float*)d_out, 10000.f + (float)(ws_size >> 20));
        return;
    }

    k_transpose<<<dim3(18, 8), 256, 0, stream>>>(wq, wk, wv, wskip, ew1, wt);
    k_tvec<<<NBATCH, H, 0, stream>>>(t_graph, time_w1, time_b1, time_w2, time_b2, tvec);
    k_init_x<<<(NN*H + 255)/256, 256, 0, stream>>>(node_emb, mask_emb, tvec, node_type,
                                                   edit_mask, node_batch, x, xb);
    k_zero_i<<<(NN + 255)/256, 256, 0, stream>>>(cnt, NN);
    k_count<<<NE/256, 256, 0, stream>>>(edst, cnt);
    k_scan<<<1, 1024, 0, stream>>>(cnt, offa, cur);
    k_scatter<<<NE/256, 256, 0, stream>>>(esrc, edst, edge_type, node_batch, cur, ssrc, seix);
    k_etab<<<NL*64, H, 0, stream>>>(edge_emb, tvec, we, etab);
    k_ctab<<<64, H, 0, stream>>>(edge_emb, tvec, ew1, eb1, ctab);

    for(int l = 0; l < NL; l++){
        GemmP P;
        P.wt[0] = wt + (size_t)(0  + l)*HH;  P.bias[0] = bq   + (size_t)l*H;  P.out[0] = Q;  P.obf[0] = 0;
        P.wt[1] = wt + (size_t)(4  + l)*HH;  P.bias[1] = bk   + (size_t)l*H;  P.out[1] = Kb; P.obf[1] = 2;
        P.wt[2] = wt + (size_t)(8  + l)*HH;  P.bias[2] = bv   + (size_t)l*H;  P.out[2] = Vb; P.obf[2] = 2;
        P.wt[3] = wt + (size_t)(12 + l)*HH;  P.bias[3] = bskip+ (size_t)l*H;  P.out[3] = XR; P.obf[3] = 0;
        k_gemm<<<dim3(63, 12), 256, 0, stream>>>(xb, P);
        k_attn<<<NN/4, 256, 0, stream>>>(Q, Kb, Vb, XR, etab + (size_t)l*64*H, offa, ssrc, seix,
                                         wbeta + (size_t)l*3*H, ln_g + (size_t)l*H,
                                         ln_b + (size_t)l*H, x, xb);
    }
    {
        GemmP P;
        P.wt[0] = wt + (size_t)16*HH; P.bias[0] = nullptr; P.out[0] = xs1; P.obf[0] = 2;
        P.wt[1] = wt + (size_t)17*HH; P.bias[1] = nullptr; P.out[1] = xd1; P.obf[1] = 2;
        P.wt[2] = P.wt[0]; P.bias[2] = nullptr; P.out[2] = xs1; P.obf[2] = 2;
        P.wt[3] = P.wt[0]; P.bias[3] = nullptr; P.out[3] = xs1; P.obf[3] = 2;
        k_gemm<<<dim3(63, 6), 256, 0, stream>>>(xb, P);
    }
    k_nodeout<<<NN/8, 256, 0, stream>>>(x, now, nob, (float*)d_out);
    k_edgemlp<<<NE/(4*EML), 256, 0, stream>>>(esrc, edst, edge_type, node_batch, xs1, xd1, ctab,
                                              ew2, eb2, (float*)d_out + (size_t)NN*32);
}

// Round 13
// 573.254 us; speedup vs baseline: 1.1468x; 1.1468x over previous
//
#include <hip/hip_runtime.h>
#include <hip/hip_bf16.h>
#include <math.h>

#define NN 16000
#define NPAD 16128
#define NE 256000
#define H 192
#define RP 256           // padded row: 64 lanes * 4 (bytes for fp8, floats for tables)
#define NL 4
#define NBATCH 8
#define VEt 8
#define HH (H*H)
#define EML 16

typedef __hip_bfloat16 bf16;
typedef unsigned short u16;
typedef unsigned char u8;
typedef unsigned int u32;
typedef __attribute__((ext_vector_type(8))) short bfrag_t;
typedef __attribute__((ext_vector_type(4))) float facc_t;
typedef __attribute__((ext_vector_type(4))) float f4;

__device__ __forceinline__ bf16 f2b(float v){ return __float2bfloat16(v); }

// ---- fp8 e4m3fn software encode, RTNE ----
__device__ __forceinline__ unsigned enc8(float x){
    unsigned u = __float_as_uint(x);
    unsigned s = (u >> 24) & 0x80u;
    float ax = fabsf(x);
    if(ax >= 448.f) return s | 0x7Eu;
    if(ax < 0.015625f){
        int q = (int)rintf(ax * 512.f);
        return s | (unsigned)q;
    }
    unsigned au = u & 0x7FFFFFFFu;
    unsigned lsb = (au >> 20) & 1u;
    au += 0x7FFFFu + lsb;
    unsigned E = (au >> 23) - 127u;
    unsigned M = (au >> 20) & 7u;
    if((int)E > 8) return s | 0x7Eu;
    return s | ((E + 7u) << 3) | M;
}
// ---- fp8 decode from dword with compile-time byte select ----
template<int SEL>
__device__ __forceinline__ float dec8s(u32 w){
#if __has_builtin(__builtin_amdgcn_cvt_f32_fp8)
    return __builtin_amdgcn_cvt_f32_fp8((int)w, SEL);
#else
    unsigned v = (w >> (SEL*8)) & 0xFFu;
    unsigned e = (v >> 3) & 15u, m = v & 7u;
    float mag = e ? __builtin_ldexpf((float)(8u + m), (int)e - 10)
                  : __builtin_ldexpf((float)m, -9);
    return (v & 0x80u) ? -mag : mag;
#endif
}
__device__ __forceinline__ float frcp(float x){
#if __has_builtin(__builtin_amdgcn_rcpf)
    return __builtin_amdgcn_rcpf(x);
#else
    return 1.f/x;
#endif
}

__global__ void k_sentinel(float* __restrict__ out, float v){ out[0] = v; }

// ---------------- transpose 18 H×H fp32 weight mats into bf16 [n][k] ----------------
__global__ void k_transpose(const float* __restrict__ wq, const float* __restrict__ wk,
                            const float* __restrict__ wv, const float* __restrict__ wsk,
                            const float* __restrict__ w1, u16* __restrict__ wt){
    int mat = blockIdx.x;
    const float* src;
    if(mat < 4)       src = wq  + (size_t)mat*HH;
    else if(mat < 8)  src = wk  + (size_t)(mat-4)*HH;
    else if(mat < 12) src = wv  + (size_t)(mat-8)*HH;
    else if(mat < 16) src = wsk + (size_t)(mat-12)*HH;
    else              src = w1  + (size_t)(mat-16)*HH;
    u16* dst = wt + (size_t)mat*HH;
    const int slice = HH/8;
    int base = blockIdx.y*slice;
    for(int i = base + threadIdx.x; i < base + slice; i += blockDim.x){
        int k = i / H, n = i % H;
        bf16 b = f2b(src[i]);
        dst[n*H + k] = *(u16*)&b;
    }
}

// ---------------- time embedding MLP ----------------
__global__ void k_tvec(const int* __restrict__ tg, const float* __restrict__ w1,
                       const float* __restrict__ b1, const float* __restrict__ w2,
                       const float* __restrict__ b2, float* __restrict__ tvec){
    int b = blockIdx.x, j = threadIdx.x;
    __shared__ float emb[H], h1[H];
    float t = (float)tg[b];
    if(j < 96){
        float fr = __expf(-logf(10000.0f) * (float)j / 96.0f);
        float ang = t * fr;
        emb[j]      = sinf(ang);
        emb[j + 96] = cosf(ang);
    }
    __syncthreads();
    float acc = b1[j];
    for(int k = 0; k < H; k++) acc += emb[k] * w1[k*H + j];
    h1[j] = acc / (1.f + __expf(-acc));
    __syncthreads();
    float acc2 = b2[j];
    for(int k = 0; k < H; k++) acc2 += h1[k] * w2[k*H + j];
    tvec[b*H + j] = acc2;
}

// ---------------- x0 ----------------
__global__ void k_init_x(const float* __restrict__ nemb, const float* __restrict__ memb,
                         const float* __restrict__ tvec, const int* __restrict__ ntype,
                         const int* __restrict__ emask, const int* __restrict__ nbatch,
                         float* __restrict__ x, u16* __restrict__ xb){
    int idx = blockIdx.x*blockDim.x + threadIdx.x;
    if(idx >= NN*H) return;
    int n = idx / H, c = idx % H;
    float v = nemb[(size_t)ntype[n]*H + c] + tvec[nbatch[n]*H + c]
            + memb[(size_t)emask[n]*H + c];
    x[idx] = v;
    bf16 b = f2b(v); xb[idx] = *(u16*)&b;
}

// ---------------- counting sort ----------------
__global__ void k_zero_i(int* __restrict__ p, int n){
    int i = blockIdx.x*blockDim.x + threadIdx.x;
    if(i < n) p[i] = 0;
}
__global__ void k_count(const int* __restrict__ edst, int* __restrict__ cnt){
    int e = blockIdx.x*blockDim.x + threadIdx.x;
    if(e < NE) atomicAdd(&cnt[edst[e]], 1);
}
__global__ __launch_bounds__(1024) void k_scan(const int* __restrict__ cnt,
                                               int* __restrict__ ofs, int* __restrict__ cur){
    __shared__ int wsum[16];
    __shared__ int carry_s;
    int tid = threadIdx.x, lane = tid & 63, w = tid >> 6;
    if(tid == 0) carry_s = 0;
    __syncthreads();
    for(int base = 0; base < NN; base += 1024){
        int idx = base + tid;
        int v = (idx < NN) ? cnt[idx] : 0;
        int sc = v;
        #pragma unroll
        for(int o = 1; o < 64; o <<= 1){
            int t = __shfl_up(sc, o);
            if(lane >= o) sc += t;
        }
        if(lane == 63) wsum[w] = sc;
        __syncthreads();
        if(w == 0){
            int ws = (lane < 16) ? wsum[lane] : 0;
            #pragma unroll
            for(int o = 1; o < 16; o <<= 1){
                int t = __shfl_up(ws, o);
                if(lane >= o) ws += t;
            }
            if(lane < 16) wsum[lane] = ws;
        }
        __syncthreads();
        int wbase = (w > 0) ? wsum[w-1] : 0;
        int c = carry_s;
        int excl = c + wbase + sc - v;
        if(idx < NN){ ofs[idx] = excl; cur[idx] = excl; }
        __syncthreads();
        if(tid == 0) carry_s = c + wsum[15];
        __syncthreads();
    }
    if(threadIdx.x == 0) ofs[NN] = carry_s;
}
__global__ void k_scatter(const int* __restrict__ esrc, const int* __restrict__ edst,
                          const int* __restrict__ etype, const int* __restrict__ nbatch,
                          int* __restrict__ cur, int* __restrict__ ssrc, int* __restrict__ seix){
    int e = blockIdx.x*blockDim.x + threadIdx.x;
    if(e >= NE) return;
    int s = esrc[e], d = edst[e];
    int pos = atomicAdd(&cur[d], 1);
    ssrc[pos] = s;
    seix[pos] = nbatch[s]*VEt + etype[e];
}

// ---------------- e-tables (padded rows: RP floats, lane*4 + t) ----------------
__global__ void k_etab(const float* __restrict__ eemb, const float* __restrict__ tvec,
                       const float* __restrict__ we, float* __restrict__ etab){
    int blk = blockIdx.x;
    int l = blk >> 6, idx = blk & 63, b = idx >> 3, et = idx & 7;
    int c = threadIdx.x;
    __shared__ float a[H];
    a[c] = eemb[et*H + c] + tvec[b*H + c];
    __syncthreads();
    float acc = 0.f;
    const float* w = we + (size_t)l*HH;
    for(int k = 0; k < H; k++) acc += a[k] * w[k*H + c];
    etab[(size_t)blk*RP + (c/3)*4 + (c%3)] = acc;
}

// ---------------- c-table (padded) ----------------
__global__ void k_ctab(const float* __restrict__ eemb, const float* __restrict__ tvec,
                       const float* __restrict__ w1, const float* __restrict__ b1,
                       float* __restrict__ ctab){
    int idx = blockIdx.x, b = idx >> 3, et = idx & 7;
    int c = threadIdx.x;
    __shared__ float a[H];
    a[c] = eemb[et*H + c] + tvec[b*H + c];
    __syncthreads();
    float acc = b1[c];
    for(int k = 0; k < H; k++){
        acc += a[k]          * w1[(size_t)(2*H + k)*H + c];
        acc += tvec[b*H + k] * w1[(size_t)(3*H + k)*H + c];
    }
    ctab[(size_t)idx*RP + (c/3)*4 + (c%3)] = acc;
}

// ---------------- MFMA GEMM; obf: 0=fp32 row-H out, 2=fp8 padded-RP out ----------------
struct GemmP {
    const u16* wt[4];
    const float* bias[4];
    void* out[4];
    int obf[4];
};
__global__ __launch_bounds__(256) void k_gemm(const u16* __restrict__ A, GemmP P){
    int oi = blockIdx.y / 3, nt = blockIdx.y % 3;
    const u16* Wt = P.wt[oi];
    const float* bias = P.bias[oi];
    int wave = threadIdx.x >> 6, lane = threadIdx.x & 63;
    int quad = lane >> 4, l16 = lane & 15;
    int m0 = blockIdx.x*256 + wave*64;
    int n0 = nt*64;
    facc_t acc[4][4];
    #pragma unroll
    for(int i = 0; i < 4; i++)
        #pragma unroll
        for(int j = 0; j < 4; j++){ acc[i][j][0]=0.f; acc[i][j][1]=0.f; acc[i][j][2]=0.f; acc[i][j][3]=0.f; }
    #pragma unroll
    for(int kc = 0; kc < 6; kc++){
        int kb = kc*32 + quad*8;
        bfrag_t af[4], bg[4];
        #pragma unroll
        for(int i = 0; i < 4; i++) af[i] = *(const bfrag_t*)(A  + (size_t)(m0 + i*16 + l16)*H + kb);
        #pragma unroll
        for(int j = 0; j < 4; j++) bg[j] = *(const bfrag_t*)(Wt + (size_t)(n0 + j*16 + l16)*H + kb);
        #pragma unroll
        for(int i = 0; i < 4; i++)
            #pragma unroll
            for(int j = 0; j < 4; j++)
                acc[i][j] = __builtin_amdgcn_mfma_f32_16x16x32_bf16(af[i], bg[j], acc[i][j], 0, 0, 0);
    }
    float bv[4];
    #pragma unroll
    for(int j = 0; j < 4; j++) bv[j] = bias ? bias[n0 + j*16 + l16] : 0.f;
    if(P.obf[oi] == 2){
        u8* out = (u8*)P.out[oi];
        int byteoff[4];
        #pragma unroll
        for(int j = 0; j < 4; j++){
            int c = n0 + j*16 + l16;
            byteoff[j] = (c/3)*4 + (c%3);
        }
        #pragma unroll
        for(int i = 0; i < 4; i++){
            int rb = m0 + i*16 + quad*4;
            #pragma unroll
            for(int r = 0; r < 4; r++){
                int row = rb + r;
                if(row < NN){
                    #pragma unroll
                    for(int j = 0; j < 4; j++)
                        out[(size_t)row*RP + byteoff[j]] = (u8)enc8(acc[i][j][r] + bv[j]);
                }
            }
        }
    } else {
        float* out = (float*)P.out[oi];
        #pragma unroll
        for(int i = 0; i < 4; i++){
            int rb = m0 + i*16 + quad*4;
            #pragma unroll
            for(int r = 0; r < 4; r++){
                int row = rb + r;
                if(row < NN){
                    #pragma unroll
                    for(int j = 0; j < 4; j++)
                        out[(size_t)row*H + n0 + j*16 + l16] = acc[i][j][r] + bv[j];
                }
            }
        }
    }
}

// ---------------- fused attention + gate + LN; no-max softmax (shift-invariant, scores tiny) ----------------
__global__ __launch_bounds__(256) void k_attn(
    const float* __restrict__ Q, const u8* __restrict__ Kb,
    const u8* __restrict__ Vb, const float* __restrict__ XR,
    const float* __restrict__ etab, const int* __restrict__ ofs,
    const int* __restrict__ ssrc, const int* __restrict__ seix,
    const float* __restrict__ wb, const float* __restrict__ lng, const float* __restrict__ lnb,
    float* __restrict__ x, u16* __restrict__ xb)
{
    int n = blockIdx.x*4 + (threadIdx.x >> 6);
    int lane = threadIdx.x & 63;
    int ch = lane*3;
    size_t base = (size_t)n*H + ch;
    const float scale = 0.14433756729740646f;   // 1/sqrt(48)
    float q0 = Q[base], q1 = Q[base+1], q2 = Q[base+2];
    int p0 = ofs[n], p1 = ofs[n+1];
    float lA = 0.f, aA0 = 0.f, aA1 = 0.f, aA2 = 0.f;
    float lB = 0.f, aB0 = 0.f, aB1 = 0.f, aB2 = 0.f;
    int p = p0;
    for(; p + 1 < p1; p += 2){
        int sA = ssrc[p],   eiA = seix[p];
        int sB = ssrc[p+1], eiB = seix[p+1];
        u32 kwA = *(const u32*)(Kb + (size_t)sA*RP + lane*4);
        u32 kwB = *(const u32*)(Kb + (size_t)sB*RP + lane*4);
        f4 efA = *(const f4*)(etab + (size_t)eiA*RP + lane*4);
        f4 efB = *(const f4*)(etab + (size_t)eiB*RP + lane*4);
        u32 vwA = *(const u32*)(Vb + (size_t)sA*RP + lane*4);
        u32 vwB = *(const u32*)(Vb + (size_t)sB*RP + lane*4);
        float tA = q0*(dec8s<0>(kwA)+efA.x) + q1*(dec8s<1>(kwA)+efA.y) + q2*(dec8s<2>(kwA)+efA.z);
        float tB = q0*(dec8s<0>(kwB)+efB.x) + q1*(dec8s<1>(kwB)+efB.y) + q2*(dec8s<2>(kwB)+efB.z);
        tA += __shfl_xor(tA,1); tB += __shfl_xor(tB,1);
        tA += __shfl_xor(tA,2); tB += __shfl_xor(tB,2);
        tA += __shfl_xor(tA,4); tB += __shfl_xor(tB,4);
        tA += __shfl_xor(tA,8); tB += __shfl_xor(tB,8);
        float scA = fminf(fmaxf(tA*scale, -60.f), 60.f);
        float scB = fminf(fmaxf(tB*scale, -60.f), 60.f);
        float pwA = __expf(scA), pwB = __expf(scB);
        lA  += pwA;                            lB  += pwB;
        aA0 += pwA*(dec8s<0>(vwA)+efA.x);      aB0 += pwB*(dec8s<0>(vwB)+efB.x);
        aA1 += pwA*(dec8s<1>(vwA)+efA.y);      aB1 += pwB*(dec8s<1>(vwB)+efB.y);
        aA2 += pwA*(dec8s<2>(vwA)+efA.z);      aB2 += pwB*(dec8s<2>(vwB)+efB.z);
    }
    if(p < p1){
        int sA = ssrc[p], eiA = seix[p];
        u32 kwA = *(const u32*)(Kb + (size_t)sA*RP + lane*4);
        f4 efA = *(const f4*)(etab + (size_t)eiA*RP + lane*4);
        u32 vwA = *(const u32*)(Vb + (size_t)sA*RP + lane*4);
        float tA = q0*(dec8s<0>(kwA)+efA.x) + q1*(dec8s<1>(kwA)+efA.y) + q2*(dec8s<2>(kwA)+efA.z);
        tA += __shfl_xor(tA,1); tA += __shfl_xor(tA,2); tA += __shfl_xor(tA,4); tA += __shfl_xor(tA,8);
        float scA = fminf(fmaxf(tA*scale, -60.f), 60.f);
        float pwA = __expf(scA);
        lA  += pwA;
        aA0 += pwA*(dec8s<0>(vwA)+efA.x);
        aA1 += pwA*(dec8s<1>(vwA)+efA.y);
        aA2 += pwA*(dec8s<2>(vwA)+efA.z);
    }
    float l  = lA + lB;
    float a0 = aA0 + aB0, a1 = aA1 + aB1, a2 = aA2 + aB2;
    float inv = (p1 > p0) ? 1.f/l : 0.f;
    float o0 = a0*inv, o1 = a1*inv, o2 = a2*inv;
    float xr0 = XR[base], xr1 = XR[base+1], xr2 = XR[base+2];
    float sd = o0*wb[ch]  + o1*wb[ch+1]  + o2*wb[ch+2]
             + xr0*wb[H+ch] + xr1*wb[H+ch+1] + xr2*wb[H+ch+2]
             + (o0-xr0)*wb[2*H+ch] + (o1-xr1)*wb[2*H+ch+1] + (o2-xr2)*wb[2*H+ch+2];
    sd += __shfl_xor(sd,1); sd += __shfl_xor(sd,2); sd += __shfl_xor(sd,4);
    sd += __shfl_xor(sd,8); sd += __shfl_xor(sd,16); sd += __shfl_xor(sd,32);
    float beta = 1.f/(1.f + __expf(-sd));
    float h0 = beta*xr0 + (1.f-beta)*o0;
    float h1 = beta*xr1 + (1.f-beta)*o1;
    float h2 = beta*xr2 + (1.f-beta)*o2;
    float y0 = x[base] + h0, y1 = x[base+1] + h1, y2 = x[base+2] + h2;
    float s3 = y0 + y1 + y2;
    s3 += __shfl_xor(s3,1); s3 += __shfl_xor(s3,2); s3 += __shfl_xor(s3,4);
    s3 += __shfl_xor(s3,8); s3 += __shfl_xor(s3,16); s3 += __shfl_xor(s3,32);
    float mean = s3 * (1.f/H);
    float d0 = y0-mean, d1 = y1-mean, d2 = y2-mean;
    float v3 = d0*d0 + d1*d1 + d2*d2;
    v3 += __shfl_xor(v3,1); v3 += __shfl_xor(v3,2); v3 += __shfl_xor(v3,4);
    v3 += __shfl_xor(v3,8); v3 += __shfl_xor(v3,16); v3 += __shfl_xor(v3,32);
    float rs = rsqrtf(v3*(1.f/H) + 1e-5f);
    float z0 = d0*rs*lng[ch]   + lnb[ch];
    float z1 = d1*rs*lng[ch+1] + lnb[ch+1];
    float z2 = d2*rs*lng[ch+2] + lnb[ch+2];
    x[base] = z0; x[base+1] = z1; x[base+2] = z2;
    bf16 t0 = f2b(z0), t1 = f2b(z1), t2 = f2b(z2);
    xb[base] = *(u16*)&t0; xb[base+1] = *(u16*)&t1; xb[base+2] = *(u16*)&t2;
}

// ---------------- node logits ----------------
__global__ void k_nodeout(const float* __restrict__ x, const float* __restrict__ w,
                          const float* __restrict__ b, float* __restrict__ out){
    int j = threadIdx.x & 31;
    int n = blockIdx.x*8 + (threadIdx.x >> 5);
    float acc = b[j];
    const float* xr = x + (size_t)n*H;
    for(int k = 0; k < H; k++) acc += xr[k] * w[k*32 + j];
    out[(size_t)n*32 + j] = acc;
}

// ---------------- edge logits: padded dword gathers, fast silu, split-butterfly ----------------
__global__ __launch_bounds__(256) void k_edgemlp(
    const int* __restrict__ esrc, const int* __restrict__ edst, const int* __restrict__ etype,
    const int* __restrict__ nb,
    const u8* __restrict__ xs1, const u8* __restrict__ xd1, const float* __restrict__ ctab,
    const float* __restrict__ w2, const float* __restrict__ b2p, float* __restrict__ out)
{
    int wid = blockIdx.x*4 + (threadIdx.x >> 6);
    int lane = threadIdx.x & 63;
    int ch = lane*3;
    float w2r[3][8];
    #pragma unroll
    for(int t = 0; t < 3; t++)
        #pragma unroll
        for(int j = 0; j < 8; j++) w2r[t][j] = w2[(ch+t)*8 + j];
    int jout = (lane&1)*4 + (lane&2) + ((lane&4)>>2);
    float bo = (lane < 8) ? b2p[jout] : 0.f;
    int b0 = lane & 1, b1 = lane & 2, b2m = lane & 4;
    int e0 = wid*EML;
    for(int e = e0; e < e0 + EML; e++){
        int s = esrc[e], d = edst[e];
        int ct = nb[s]*VEt + etype[e];
        u32 aw = *(const u32*)(xs1 + (size_t)s*RP + lane*4);
        u32 bw = *(const u32*)(xd1 + (size_t)d*RP + lane*4);
        f4  cf = *(const f4*)(ctab + (size_t)ct*RP + lane*4);
        float h0, h1, h2;
        { float v = dec8s<0>(aw)+dec8s<0>(bw)+cf.x; h0 = v*frcp(1.f+__expf(-v)); }
        { float v = dec8s<1>(aw)+dec8s<1>(bw)+cf.y; h1 = v*frcp(1.f+__expf(-v)); }
        { float v = dec8s<2>(aw)+dec8s<2>(bw)+cf.z; h2 = v*frcp(1.f+__expf(-v)); }
        float pj[8];
        #pragma unroll
        for(int j = 0; j < 8; j++)
            pj[j] = h0*w2r[0][j] + h1*w2r[1][j] + h2*w2r[2][j];
        float v4[4];
        #pragma unroll
        for(int t = 0; t < 4; t++){
            float send = b0 ? pj[t] : pj[t+4];
            float keep = b0 ? pj[t+4] : pj[t];
            v4[t] = keep + __shfl_xor(send, 1);
        }
        float v2[2];
        #pragma unroll
        for(int t = 0; t < 2; t++){
            float send = b1 ? v4[t] : v4[t+2];
            float keep = b1 ? v4[t+2] : v4[t];
            v2[t] = keep + __shfl_xor(send, 2);
        }
        float v1;
        {
            float send = b2m ? v2[0] : v2[1];
            float keep = b2m ? v2[1] : v2[0];
            v1 = keep + __shfl_xor(send, 4);
        }
        v1 += __shfl_xor(v1, 8); v1 += __shfl_xor(v1, 16); v1 += __shfl_xor(v1, 32);
        if(lane < 8) out[(size_t)e*8 + jout] = v1 + bo;
    }
}

extern "C" void kernel_launch(void* const* d_in, const int* in_sizes, int n_in,
                              void* d_out, int out_size, void* d_ws, size_t ws_size,
                              hipStream_t stream)
{
    {
        int bad = -1;
        if(n_in != 31) bad = 100;
        else {
            const int chk_idx[9] = {0, 7, 16, 21, 23, 26, 27, 29, 30};
            const int chk_sz [9] = {32*H, NL*HH, NL*3*H, 4*HH, H*8, NE, 2*NE, NN, NBATCH};
            for(int i = 0; i < 9; i++) if(in_sizes[chk_idx[i]] != chk_sz[i]){ bad = chk_idx[i]; break; }
        }
        if(bad >= 0){ k_sentinel<<<1,1,0,stream>>>((float*)d_out, 20000.f + 256.f*bad); return; }
        if(out_size != NN*32 + NE*8){ k_sentinel<<<1,1,0,stream>>>((float*)d_out, 30000.f); return; }
    }

    const float* node_emb = (const float*)d_in[0];
    const float* edge_emb = (const float*)d_in[1];
    const float* time_w1  = (const float*)d_in[2];
    const float* time_b1  = (const float*)d_in[3];
    const float* time_w2  = (const float*)d_in[4];
    const float* time_b2  = (const float*)d_in[5];
    const float* mask_emb = (const float*)d_in[6];
    const float* wq       = (const float*)d_in[7];
    const float* bq       = (const float*)d_in[8];
    const float* wk       = (const float*)d_in[9];
    const float* bk       = (const float*)d_in[10];
    const float* wv       = (const float*)d_in[11];
    const float* bv       = (const float*)d_in[12];
    const float* we       = (const float*)d_in[13];
    const float* wskip    = (const float*)d_in[14];
    const float* bskip    = (const float*)d_in[15];
    const float* wbeta    = (const float*)d_in[16];
    const float* ln_g     = (const float*)d_in[17];
    const float* ln_b     = (const float*)d_in[18];
    const float* now      = (const float*)d_in[19];
    const float* nob      = (const float*)d_in[20];
    const float* ew1      = (const float*)d_in[21];
    const float* eb1      = (const float*)d_in[22];
    const float* ew2      = (const float*)d_in[23];
    const float* eb2      = (const float*)d_in[24];
    const int* node_type  = (const int*)d_in[25];
    const int* edge_type  = (const int*)d_in[26];
    const int* edge_index = (const int*)d_in[27];
    const int* edit_mask  = (const int*)d_in[28];
    const int* node_batch = (const int*)d_in[29];
    const int* t_graph    = (const int*)d_in[30];
    const int* esrc = edge_index;
    const int* edst = edge_index + NE;

    char* wsb = (char*)d_ws;
    size_t off = 0;
    auto take = [&](size_t bytes) -> char* {
        char* r = wsb + off;
        off += (bytes + 255) & ~(size_t)255;
        return r;
    };
    float* tvec = (float*)take((size_t)NBATCH*H*4);
    float* x    = (float*)take((size_t)NN*H*4);
    u16*   xb   = (u16*)  take((size_t)NPAD*H*2);
    float* Q    = (float*)take((size_t)NN*H*4);
    u8*    Kb   = (u8*)   take((size_t)NN*RP);
    u8*    Vb   = (u8*)   take((size_t)NN*RP);
    float* XR   = (float*)take((size_t)NN*H*4);
    u8*    xs1  = (u8*)   take((size_t)NN*RP);
    u8*    xd1  = (u8*)   take((size_t)NN*RP);
    float* etab = (float*)take((size_t)NL*64*RP*4);
    float* ctab = (float*)take((size_t)64*RP*4);
    u16*   wt   = (u16*)  take((size_t)18*HH*2);
    int* cnt    = (int*)  take((size_t)(NN+1)*4);
    int* offa   = (int*)  take((size_t)(NN+1)*4);
    int* cur    = (int*)  take((size_t)(NN+1)*4);
    int* ssrc   = (int*)  take((size_t)NE*4);
    int* seix   = (int*)  take((size_t)NE*4);

    if(ws_size < off){
        k_sentinel<<<1,1,0,stream>>>((float*)d_out, 10000.f + (float)(ws_size >> 20));
        return;
    }

    k_transpose<<<dim3(18, 8), 256, 0, stream>>>(wq, wk, wv, wskip, ew1, wt);
    k_tvec<<<NBATCH, H, 0, stream>>>(t_graph, time_w1, time_b1, time_w2, time_b2, tvec);
    k_init_x<<<(NN*H + 255)/256, 256, 0, stream>>>(node_emb, mask_emb, tvec, node_type,
                                                   edit_mask, node_batch, x, xb);
    k_zero_i<<<(NN + 255)/256, 256, 0, stream>>>(cnt, NN);
    k_count<<<NE/256, 256, 0, stream>>>(edst, cnt);
    k_scan<<<1, 1024, 0, stream>>>(cnt, offa, cur);
    k_scatter<<<NE/256, 256, 0, stream>>>(esrc, edst, edge_type, node_batch, cur, ssrc, seix);
    k_etab<<<NL*64, H, 0, stream>>>(edge_emb, tvec, we, etab);
    k_ctab<<<64, H, 0, stream>>>(edge_emb, tvec, ew1, eb1, ctab);

    for(int l = 0; l < NL; l++){
        GemmP P;
        P.wt[0] = wt + (size_t)(0  + l)*HH;  P.bias[0] = bq   + (size_t)l*H;  P.out[0] = Q;  P.obf[0] = 0;
        P.wt[1] = wt + (size_t)(4  + l)*HH;  P.bias[1] = bk   + (size_t)l*H;  P.out[1] = Kb; P.obf[1] = 2;
        P.wt[2] = wt + (size_t)(8  + l)*HH;  P.bias[2] = bv   + (size_t)l*H;  P.out[2] = Vb; P.obf[2] = 2;
        P.wt[3] = wt + (size_t)(12 + l)*HH;  P.bias[3] = bskip+ (size_t)l*H;  P.out[3] = XR; P.obf[3] = 0;
        k_gemm<<<dim3(63, 12), 256, 0, stream>>>(xb, P);
        k_attn<<<NN/4, 256, 0, stream>>>(Q, Kb, Vb, XR, etab + (size_t)l*64*RP, offa, ssrc, seix,
                                         wbeta + (size_t)l*3*H, ln_g + (size_t)l*H,
                                         ln_b + (size_t)l*H, x, xb);
    }
    {
        GemmP P;
        P.wt[0] = wt + (size_t)16*HH; P.bias[0] = nullptr; P.out[0] = xs1; P.obf[0] = 2;
        P.wt[1] = wt + (size_t)17*HH; P.bias[1] = nullptr; P.out[1] = xd1; P.obf[1] = 2;
        P.wt[2] = P.wt[0]; P.bias[2] = nullptr; P.out[2] = xs1; P.obf[2] = 2;
        P.wt[3] = P.wt[0]; P.bias[3] = nullptr; P.out[3] = xs1; P.obf[3] = 2;
        k_gemm<<<dim3(63, 6), 256, 0, stream>>>(xb, P);
    }
    k_nodeout<<<NN/8, 256, 0, stream>>>(x, now, nob, (float*)d_out);
    k_edgemlp<<<NE/(4*EML), 256, 0, stream>>>(esrc, edst, edge_type, node_batch, xs1, xd1, ctab,
                                              ew2, eb2, (float*)d_out + (size_t)NN*32);
}

// Round 14
// 552.090 us; speedup vs baseline: 1.1908x; 1.0383x over previous
//
#include <hip/hip_runtime.h>
#include <hip/hip_bf16.h>
#include <math.h>

#define NN 16000
#define NPAD 16128
#define NE 256000
#define H 192
#define RP 256           // padded row: 64 lanes * 4 (bytes for fp8, floats for tables)
#define NL 4
#define NBATCH 8
#define VEt 8
#define HH (H*H)
#define EML 16

typedef __hip_bfloat16 bf16;
typedef unsigned short u16;
typedef unsigned char u8;
typedef unsigned int u32;
typedef __attribute__((ext_vector_type(8))) short bfrag_t;
typedef __attribute__((ext_vector_type(4))) float facc_t;
typedef __attribute__((ext_vector_type(4))) float f4;

__device__ __forceinline__ bf16 f2b(float v){ return __float2bfloat16(v); }

// ---- fp8 e4m3fn software encode, RTNE (fallback) ----
__device__ __forceinline__ unsigned enc8sw(float x){
    unsigned u = __float_as_uint(x);
    unsigned s = (u >> 24) & 0x80u;
    float ax = fabsf(x);
    if(ax >= 448.f) return s | 0x7Eu;
    if(ax < 0.015625f){
        int q = (int)rintf(ax * 512.f);
        return s | (unsigned)q;
    }
    unsigned au = u & 0x7FFFFFFFu;
    unsigned lsb = (au >> 20) & 1u;
    au += 0x7FFFFu + lsb;
    unsigned E = (au >> 23) - 127u;
    unsigned M = (au >> 20) & 7u;
    if((int)E > 8) return s | 0x7Eu;
    return s | ((E + 7u) << 3) | M;
}
// ---- fp8 encode, HW packed convert if available ----
__device__ __forceinline__ unsigned enc8(float x){
#if __has_builtin(__builtin_amdgcn_cvt_pk_fp8_f32)
    return (u32)__builtin_amdgcn_cvt_pk_fp8_f32(x, x, 0, false) & 0xFFu;
#else
    return enc8sw(x);
#endif
}
// ---- fp8 decode from dword with compile-time byte select ----
template<int SEL>
__device__ __forceinline__ float dec8s(u32 w){
#if __has_builtin(__builtin_amdgcn_cvt_f32_fp8)
    return __builtin_amdgcn_cvt_f32_fp8((int)w, SEL);
#else
    unsigned v = (w >> (SEL*8)) & 0xFFu;
    unsigned e = (v >> 3) & 15u, m = v & 7u;
    float mag = e ? __builtin_ldexpf((float)(8u + m), (int)e - 10)
                  : __builtin_ldexpf((float)m, -9);
    return (v & 0x80u) ? -mag : mag;
#endif
}
__device__ __forceinline__ float frcp(float x){
#if __has_builtin(__builtin_amdgcn_rcpf)
    return __builtin_amdgcn_rcpf(x);
#else
    return 1.f/x;
#endif
}

__global__ void k_sentinel(float* __restrict__ out, float v){ out[0] = v; }

// ---------------- transpose 18 H×H fp32 weight mats into bf16 [n][k] ----------------
__global__ void k_transpose(const float* __restrict__ wq, const float* __restrict__ wk,
                            const float* __restrict__ wv, const float* __restrict__ wsk,
                            const float* __restrict__ w1, u16* __restrict__ wt){
    int mat = blockIdx.x;
    const float* src;
    if(mat < 4)       src = wq  + (size_t)mat*HH;
    else if(mat < 8)  src = wk  + (size_t)(mat-4)*HH;
    else if(mat < 12) src = wv  + (size_t)(mat-8)*HH;
    else if(mat < 16) src = wsk + (size_t)(mat-12)*HH;
    else              src = w1  + (size_t)(mat-16)*HH;
    u16* dst = wt + (size_t)mat*HH;
    const int slice = HH/8;
    int base = blockIdx.y*slice;
    for(int i = base + threadIdx.x; i < base + slice; i += blockDim.x){
        int k = i / H, n = i % H;
        bf16 b = f2b(src[i]);
        dst[n*H + k] = *(u16*)&b;
    }
}

// ---------------- time embedding MLP ----------------
__global__ void k_tvec(const int* __restrict__ tg, const float* __restrict__ w1,
                       const float* __restrict__ b1, const float* __restrict__ w2,
                       const float* __restrict__ b2, float* __restrict__ tvec){
    int b = blockIdx.x, j = threadIdx.x;
    __shared__ float emb[H], h1[H];
    float t = (float)tg[b];
    if(j < 96){
        float fr = __expf(-logf(10000.0f) * (float)j / 96.0f);
        float ang = t * fr;
        emb[j]      = sinf(ang);
        emb[j + 96] = cosf(ang);
    }
    __syncthreads();
    float acc = b1[j];
    for(int k = 0; k < H; k++) acc += emb[k] * w1[k*H + j];
    h1[j] = acc / (1.f + __expf(-acc));
    __syncthreads();
    float acc2 = b2[j];
    for(int k = 0; k < H; k++) acc2 += h1[k] * w2[k*H + j];
    tvec[b*H + j] = acc2;
}

// ---------------- x0 ----------------
__global__ void k_init_x(const float* __restrict__ nemb, const float* __restrict__ memb,
                         const float* __restrict__ tvec, const int* __restrict__ ntype,
                         const int* __restrict__ emask, const int* __restrict__ nbatch,
                         float* __restrict__ x, u16* __restrict__ xb){
    int idx = blockIdx.x*blockDim.x + threadIdx.x;
    if(idx >= NN*H) return;
    int n = idx / H, c = idx % H;
    float v = nemb[(size_t)ntype[n]*H + c] + tvec[nbatch[n]*H + c]
            + memb[(size_t)emask[n]*H + c];
    x[idx] = v;
    bf16 b = f2b(v); xb[idx] = *(u16*)&b;
}

// ---------------- counting sort ----------------
__global__ void k_zero_i(int* __restrict__ p, int n){
    int i = blockIdx.x*blockDim.x + threadIdx.x;
    if(i < n) p[i] = 0;
}
__global__ void k_count(const int* __restrict__ edst, int* __restrict__ cnt){
    int e = blockIdx.x*blockDim.x + threadIdx.x;
    if(e < NE) atomicAdd(&cnt[edst[e]], 1);
}
__global__ __launch_bounds__(1024) void k_scan(const int* __restrict__ cnt,
                                               int* __restrict__ ofs, int* __restrict__ cur){
    __shared__ int wsum[16];
    __shared__ int carry_s;
    int tid = threadIdx.x, lane = tid & 63, w = tid >> 6;
    if(tid == 0) carry_s = 0;
    __syncthreads();
    for(int base = 0; base < NN; base += 1024){
        int idx = base + tid;
        int v = (idx < NN) ? cnt[idx] : 0;
        int sc = v;
        #pragma unroll
        for(int o = 1; o < 64; o <<= 1){
            int t = __shfl_up(sc, o);
            if(lane >= o) sc += t;
        }
        if(lane == 63) wsum[w] = sc;
        __syncthreads();
        if(w == 0){
            int ws = (lane < 16) ? wsum[lane] : 0;
            #pragma unroll
            for(int o = 1; o < 16; o <<= 1){
                int t = __shfl_up(ws, o);
                if(lane >= o) ws += t;
            }
            if(lane < 16) wsum[lane] = ws;
        }
        __syncthreads();
        int wbase = (w > 0) ? wsum[w-1] : 0;
        int c = carry_s;
        int excl = c + wbase + sc - v;
        if(idx < NN){ ofs[idx] = excl; cur[idx] = excl; }
        __syncthreads();
        if(tid == 0) carry_s = c + wsum[15];
        __syncthreads();
    }
    if(threadIdx.x == 0) ofs[NN] = carry_s;
}
__global__ void k_scatter(const int* __restrict__ esrc, const int* __restrict__ edst,
                          const int* __restrict__ etype, const int* __restrict__ nbatch,
                          int* __restrict__ cur, int* __restrict__ ssrc, int* __restrict__ seix){
    int e = blockIdx.x*blockDim.x + threadIdx.x;
    if(e >= NE) return;
    int s = esrc[e], d = edst[e];
    int pos = atomicAdd(&cur[d], 1);
    ssrc[pos] = s;
    seix[pos] = nbatch[s]*VEt + etype[e];
}

// ---------------- e-tables (padded rows: RP floats, lane*4 + t) ----------------
__global__ void k_etab(const float* __restrict__ eemb, const float* __restrict__ tvec,
                       const float* __restrict__ we, float* __restrict__ etab){
    int blk = blockIdx.x;
    int l = blk >> 6, idx = blk & 63, b = idx >> 3, et = idx & 7;
    int c = threadIdx.x;
    __shared__ float a[H];
    a[c] = eemb[et*H + c] + tvec[b*H + c];
    __syncthreads();
    float acc = 0.f;
    const float* w = we + (size_t)l*HH;
    for(int k = 0; k < H; k++) acc += a[k] * w[k*H + c];
    etab[(size_t)blk*RP + (c/3)*4 + (c%3)] = acc;
}

// ---------------- c-table (padded) ----------------
__global__ void k_ctab(const float* __restrict__ eemb, const float* __restrict__ tvec,
                       const float* __restrict__ w1, const float* __restrict__ b1,
                       float* __restrict__ ctab){
    int idx = blockIdx.x, b = idx >> 3, et = idx & 7;
    int c = threadIdx.x;
    __shared__ float a[H];
    a[c] = eemb[et*H + c] + tvec[b*H + c];
    __syncthreads();
    float acc = b1[c];
    for(int k = 0; k < H; k++){
        acc += a[k]          * w1[(size_t)(2*H + k)*H + c];
        acc += tvec[b*H + k] * w1[(size_t)(3*H + k)*H + c];
    }
    ctab[(size_t)idx*RP + (c/3)*4 + (c%3)] = acc;
}

// ---------------- MFMA GEMM; obf: 0=fp32 row-H out, 2=fp8 padded-RP out ----------------
struct GemmP {
    const u16* wt[4];
    const float* bias[4];
    void* out[4];
    int obf[4];
};
__global__ __launch_bounds__(256) void k_gemm(const u16* __restrict__ A, GemmP P){
    int oi = blockIdx.y / 3, nt = blockIdx.y % 3;
    const u16* Wt = P.wt[oi];
    const float* bias = P.bias[oi];
    int wave = threadIdx.x >> 6, lane = threadIdx.x & 63;
    int quad = lane >> 4, l16 = lane & 15;
    int m0 = blockIdx.x*256 + wave*64;
    int n0 = nt*64;
    facc_t acc[4][4];
    #pragma unroll
    for(int i = 0; i < 4; i++)
        #pragma unroll
        for(int j = 0; j < 4; j++){ acc[i][j][0]=0.f; acc[i][j][1]=0.f; acc[i][j][2]=0.f; acc[i][j][3]=0.f; }
    #pragma unroll
    for(int kc = 0; kc < 6; kc++){
        int kb = kc*32 + quad*8;
        bfrag_t af[4], bg[4];
        #pragma unroll
        for(int i = 0; i < 4; i++) af[i] = *(const bfrag_t*)(A  + (size_t)(m0 + i*16 + l16)*H + kb);
        #pragma unroll
        for(int j = 0; j < 4; j++) bg[j] = *(const bfrag_t*)(Wt + (size_t)(n0 + j*16 + l16)*H + kb);
        #pragma unroll
        for(int i = 0; i < 4; i++)
            #pragma unroll
            for(int j = 0; j < 4; j++)
                acc[i][j] = __builtin_amdgcn_mfma_f32_16x16x32_bf16(af[i], bg[j], acc[i][j], 0, 0, 0);
    }
    float bv[4];
    #pragma unroll
    for(int j = 0; j < 4; j++) bv[j] = bias ? bias[n0 + j*16 + l16] : 0.f;
    if(P.obf[oi] == 2){
        u8* out = (u8*)P.out[oi];
        int byteoff[4];
        #pragma unroll
        for(int j = 0; j < 4; j++){
            int c = n0 + j*16 + l16;
            byteoff[j] = (c/3)*4 + (c%3);
        }
        #pragma unroll
        for(int i = 0; i < 4; i++){
            int rb = m0 + i*16 + quad*4;
            #pragma unroll
            for(int r = 0; r < 4; r++){
                int row = rb + r;
                if(row < NN){
                    #pragma unroll
                    for(int j = 0; j < 4; j++)
                        out[(size_t)row*RP + byteoff[j]] = (u8)enc8(acc[i][j][r] + bv[j]);
                }
            }
        }
    } else {
        float* out = (float*)P.out[oi];
        #pragma unroll
        for(int i = 0; i < 4; i++){
            int rb = m0 + i*16 + quad*4;
            #pragma unroll
            for(int r = 0; r < 4; r++){
                int row = rb + r;
                if(row < NN){
                    #pragma unroll
                    for(int j = 0; j < 4; j++)
                        out[(size_t)row*H + n0 + j*16 + l16] = acc[i][j][r] + bv[j];
                }
            }
        }
    }
}

// ---------------- fused attention + gate + LN; no-max softmax, 4-stream ----------------
__global__ __launch_bounds__(256) void k_attn(
    const float* __restrict__ Q, const u8* __restrict__ Kb,
    const u8* __restrict__ Vb, const float* __restrict__ XR,
    const float* __restrict__ etab, const int* __restrict__ ofs,
    const int* __restrict__ ssrc, const int* __restrict__ seix,
    const float* __restrict__ wb, const float* __restrict__ lng, const float* __restrict__ lnb,
    float* __restrict__ x, u16* __restrict__ xb)
{
    int n = blockIdx.x*4 + (threadIdx.x >> 6);
    int lane = threadIdx.x & 63;
    int ch = lane*3;
    size_t base = (size_t)n*H + ch;
    const float scale = 0.14433756729740646f;   // 1/sqrt(48)
    float q0 = Q[base], q1 = Q[base+1], q2 = Q[base+2];
    int p0 = ofs[n], p1 = ofs[n+1];
    float lac[4]  = {0.f,0.f,0.f,0.f};
    float ac0[4]  = {0.f,0.f,0.f,0.f};
    float ac1[4]  = {0.f,0.f,0.f,0.f};
    float ac2[4]  = {0.f,0.f,0.f,0.f};
    int p = p0;
    for(; p + 3 < p1; p += 4){
        int s[4], ei[4];
        #pragma unroll
        for(int t = 0; t < 4; t++){ s[t] = ssrc[p+t]; ei[t] = seix[p+t]; }
        u32 kw[4], vw[4];
        f4 ef[4];
        #pragma unroll
        for(int t = 0; t < 4; t++){
            kw[t] = *(const u32*)(Kb + (size_t)s[t]*RP + lane*4);
            ef[t] = *(const f4*)(etab + (size_t)ei[t]*RP + lane*4);
            vw[t] = *(const u32*)(Vb + (size_t)s[t]*RP + lane*4);
        }
        float tt[4];
        #pragma unroll
        for(int t = 0; t < 4; t++)
            tt[t] = q0*(dec8s<0>(kw[t])+ef[t].x) + q1*(dec8s<1>(kw[t])+ef[t].y)
                  + q2*(dec8s<2>(kw[t])+ef[t].z);
        #pragma unroll
        for(int o = 1; o <= 8; o <<= 1){
            #pragma unroll
            for(int t = 0; t < 4; t++) tt[t] += __shfl_xor(tt[t], o);
        }
        #pragma unroll
        for(int t = 0; t < 4; t++){
            float sc = fminf(fmaxf(tt[t]*scale, -60.f), 60.f);
            float pw = __expf(sc);
            lac[t] += pw;
            ac0[t] += pw*(dec8s<0>(vw[t])+ef[t].x);
            ac1[t] += pw*(dec8s<1>(vw[t])+ef[t].y);
            ac2[t] += pw*(dec8s<2>(vw[t])+ef[t].z);
        }
    }
    for(; p < p1; p++){
        int sA = ssrc[p], eiA = seix[p];
        u32 kwA = *(const u32*)(Kb + (size_t)sA*RP + lane*4);
        f4 efA = *(const f4*)(etab + (size_t)eiA*RP + lane*4);
        u32 vwA = *(const u32*)(Vb + (size_t)sA*RP + lane*4);
        float tA = q0*(dec8s<0>(kwA)+efA.x) + q1*(dec8s<1>(kwA)+efA.y) + q2*(dec8s<2>(kwA)+efA.z);
        tA += __shfl_xor(tA,1); tA += __shfl_xor(tA,2); tA += __shfl_xor(tA,4); tA += __shfl_xor(tA,8);
        float sc = fminf(fmaxf(tA*scale, -60.f), 60.f);
        float pw = __expf(sc);
        lac[0] += pw;
        ac0[0] += pw*(dec8s<0>(vwA)+efA.x);
        ac1[0] += pw*(dec8s<1>(vwA)+efA.y);
        ac2[0] += pw*(dec8s<2>(vwA)+efA.z);
    }
    float l  = (lac[0]+lac[1]) + (lac[2]+lac[3]);
    float a0 = (ac0[0]+ac0[1]) + (ac0[2]+ac0[3]);
    float a1 = (ac1[0]+ac1[1]) + (ac1[2]+ac1[3]);
    float a2 = (ac2[0]+ac2[1]) + (ac2[2]+ac2[3]);
    float inv = (p1 > p0) ? 1.f/l : 0.f;
    float o0 = a0*inv, o1 = a1*inv, o2 = a2*inv;
    float xr0 = XR[base], xr1 = XR[base+1], xr2 = XR[base+2];
    float sd = o0*wb[ch]  + o1*wb[ch+1]  + o2*wb[ch+2]
             + xr0*wb[H+ch] + xr1*wb[H+ch+1] + xr2*wb[H+ch+2]
             + (o0-xr0)*wb[2*H+ch] + (o1-xr1)*wb[2*H+ch+1] + (o2-xr2)*wb[2*H+ch+2];
    sd += __shfl_xor(sd,1); sd += __shfl_xor(sd,2); sd += __shfl_xor(sd,4);
    sd += __shfl_xor(sd,8); sd += __shfl_xor(sd,16); sd += __shfl_xor(sd,32);
    float beta = 1.f/(1.f + __expf(-sd));
    float h0 = beta*xr0 + (1.f-beta)*o0;
    float h1 = beta*xr1 + (1.f-beta)*o1;
    float h2 = beta*xr2 + (1.f-beta)*o2;
    float y0 = x[base] + h0, y1 = x[base+1] + h1, y2 = x[base+2] + h2;
    float s3 = y0 + y1 + y2;
    s3 += __shfl_xor(s3,1); s3 += __shfl_xor(s3,2); s3 += __shfl_xor(s3,4);
    s3 += __shfl_xor(s3,8); s3 += __shfl_xor(s3,16); s3 += __shfl_xor(s3,32);
    float mean = s3 * (1.f/H);
    float d0 = y0-mean, d1 = y1-mean, d2 = y2-mean;
    float v3 = d0*d0 + d1*d1 + d2*d2;
    v3 += __shfl_xor(v3,1); v3 += __shfl_xor(v3,2); v3 += __shfl_xor(v3,4);
    v3 += __shfl_xor(v3,8); v3 += __shfl_xor(v3,16); v3 += __shfl_xor(v3,32);
    float rs = rsqrtf(v3*(1.f/H) + 1e-5f);
    float z0 = d0*rs*lng[ch]   + lnb[ch];
    float z1 = d1*rs*lng[ch+1] + lnb[ch+1];
    float z2 = d2*rs*lng[ch+2] + lnb[ch+2];
    x[base] = z0; x[base+1] = z1; x[base+2] = z2;
    bf16 t0 = f2b(z0), t1 = f2b(z1), t2 = f2b(z2);
    xb[base] = *(u16*)&t0; xb[base+1] = *(u16*)&t1; xb[base+2] = *(u16*)&t2;
}

// ---------------- node logits ----------------
__global__ void k_nodeout(const float* __restrict__ x, const float* __restrict__ w,
                          const float* __restrict__ b, float* __restrict__ out){
    int j = threadIdx.x & 31;
    int n = blockIdx.x*8 + (threadIdx.x >> 5);
    float acc = b[j];
    const float* xr = x + (size_t)n*H;
    for(int k = 0; k < H; k++) acc += xr[k] * w[k*32 + j];
    out[(size_t)n*32 + j] = acc;
}

// ---------------- edge logits: 2-edge interleave, padded dword gathers ----------------
__global__ __launch_bounds__(256) void k_edgemlp(
    const int* __restrict__ esrc, const int* __restrict__ edst, const int* __restrict__ etype,
    const int* __restrict__ nb,
    const u8* __restrict__ xs1, const u8* __restrict__ xd1, const float* __restrict__ ctab,
    const float* __restrict__ w2, const float* __restrict__ b2p, float* __restrict__ out)
{
    int wid = blockIdx.x*4 + (threadIdx.x >> 6);
    int lane = threadIdx.x & 63;
    int ch = lane*3;
    float w2r[3][8];
    #pragma unroll
    for(int t = 0; t < 3; t++)
        #pragma unroll
        for(int j = 0; j < 8; j++) w2r[t][j] = w2[(ch+t)*8 + j];
    int jout = (lane&1)*4 + (lane&2) + ((lane&4)>>2);
    float bo = (lane < 8) ? b2p[jout] : 0.f;
    int b0 = lane & 1, b1 = lane & 2, b2m = lane & 4;
    int e0 = wid*EML;
    for(int eb = e0; eb < e0 + EML; eb += 2){
        int sX = esrc[eb],   dX = edst[eb];
        int sY = esrc[eb+1], dY = edst[eb+1];
        int ctX = nb[sX]*VEt + etype[eb];
        int ctY = nb[sY]*VEt + etype[eb+1];
        u32 awX = *(const u32*)(xs1 + (size_t)sX*RP + lane*4);
        u32 awY = *(const u32*)(xs1 + (size_t)sY*RP + lane*4);
        u32 bwX = *(const u32*)(xd1 + (size_t)dX*RP + lane*4);
        u32 bwY = *(const u32*)(xd1 + (size_t)dY*RP + lane*4);
        f4  cfX = *(const f4*)(ctab + (size_t)ctX*RP + lane*4);
        f4  cfY = *(const f4*)(ctab + (size_t)ctY*RP + lane*4);
        float hX0, hX1, hX2, hY0, hY1, hY2;
        { float v = dec8s<0>(awX)+dec8s<0>(bwX)+cfX.x; hX0 = v*frcp(1.f+__expf(-v)); }
        { float v = dec8s<1>(awX)+dec8s<1>(bwX)+cfX.y; hX1 = v*frcp(1.f+__expf(-v)); }
        { float v = dec8s<2>(awX)+dec8s<2>(bwX)+cfX.z; hX2 = v*frcp(1.f+__expf(-v)); }
        { float v = dec8s<0>(awY)+dec8s<0>(bwY)+cfY.x; hY0 = v*frcp(1.f+__expf(-v)); }
        { float v = dec8s<1>(awY)+dec8s<1>(bwY)+cfY.y; hY1 = v*frcp(1.f+__expf(-v)); }
        { float v = dec8s<2>(awY)+dec8s<2>(bwY)+cfY.z; hY2 = v*frcp(1.f+__expf(-v)); }
        float pjX[8], pjY[8];
        #pragma unroll
        for(int j = 0; j < 8; j++){
            pjX[j] = hX0*w2r[0][j] + hX1*w2r[1][j] + hX2*w2r[2][j];
            pjY[j] = hY0*w2r[0][j] + hY1*w2r[1][j] + hY2*w2r[2][j];
        }
        float v4X[4], v4Y[4];
        #pragma unroll
        for(int t = 0; t < 4; t++){
            float sX4 = b0 ? pjX[t] : pjX[t+4];
            float kX4 = b0 ? pjX[t+4] : pjX[t];
            v4X[t] = kX4 + __shfl_xor(sX4, 1);
            float sY4 = b0 ? pjY[t] : pjY[t+4];
            float kY4 = b0 ? pjY[t+4] : pjY[t];
            v4Y[t] = kY4 + __shfl_xor(sY4, 1);
        }
        float v2X[2], v2Y[2];
        #pragma unroll
        for(int t = 0; t < 2; t++){
            float sX2 = b1 ? v4X[t] : v4X[t+2];
            float kX2 = b1 ? v4X[t+2] : v4X[t];
            v2X[t] = kX2 + __shfl_xor(sX2, 2);
            float sY2 = b1 ? v4Y[t] : v4Y[t+2];
            float kY2 = b1 ? v4Y[t+2] : v4Y[t];
            v2Y[t] = kY2 + __shfl_xor(sY2, 2);
        }
        float v1X, v1Y;
        {
            float sX1 = b2m ? v2X[0] : v2X[1];
            float kX1 = b2m ? v2X[1] : v2X[0];
            v1X = kX1 + __shfl_xor(sX1, 4);
            float sY1 = b2m ? v2Y[0] : v2Y[1];
            float kY1 = b2m ? v2Y[1] : v2Y[0];
            v1Y = kY1 + __shfl_xor(sY1, 4);
        }
        v1X += __shfl_xor(v1X, 8);  v1Y += __shfl_xor(v1Y, 8);
        v1X += __shfl_xor(v1X, 16); v1Y += __shfl_xor(v1Y, 16);
        v1X += __shfl_xor(v1X, 32); v1Y += __shfl_xor(v1Y, 32);
        if(lane < 8){
            out[(size_t)eb*8 + jout]     = v1X + bo;
            out[(size_t)(eb+1)*8 + jout] = v1Y + bo;
        }
    }
}

extern "C" void kernel_launch(void* const* d_in, const int* in_sizes, int n_in,
                              void* d_out, int out_size, void* d_ws, size_t ws_size,
                              hipStream_t stream)
{
    {
        int bad = -1;
        if(n_in != 31) bad = 100;
        else {
            const int chk_idx[9] = {0, 7, 16, 21, 23, 26, 27, 29, 30};
            const int chk_sz [9] = {32*H, NL*HH, NL*3*H, 4*HH, H*8, NE, 2*NE, NN, NBATCH};
            for(int i = 0; i < 9; i++) if(in_sizes[chk_idx[i]] != chk_sz[i]){ bad = chk_idx[i]; break; }
        }
        if(bad >= 0){ k_sentinel<<<1,1,0,stream>>>((float*)d_out, 20000.f + 256.f*bad); return; }
        if(out_size != NN*32 + NE*8){ k_sentinel<<<1,1,0,stream>>>((float*)d_out, 30000.f); return; }
    }

    const float* node_emb = (const float*)d_in[0];
    const float* edge_emb = (const float*)d_in[1];
    const float* time_w1  = (const float*)d_in[2];
    const float* time_b1  = (const float*)d_in[3];
    const float* time_w2  = (const float*)d_in[4];
    const float* time_b2  = (const float*)d_in[5];
    const float* mask_emb = (const float*)d_in[6];
    const float* wq       = (const float*)d_in[7];
    const float* bq       = (const float*)d_in[8];
    const float* wk       = (const float*)d_in[9];
    const float* bk       = (const float*)d_in[10];
    const float* wv       = (const float*)d_in[11];
    const float* bv       = (const float*)d_in[12];
    const float* we       = (const float*)d_in[13];
    const float* wskip    = (const float*)d_in[14];
    const float* bskip    = (const float*)d_in[15];
    const float* wbeta    = (const float*)d_in[16];
    const float* ln_g     = (const float*)d_in[17];
    const float* ln_b     = (const float*)d_in[18];
    const float* now      = (const float*)d_in[19];
    const float* nob      = (const float*)d_in[20];
    const float* ew1      = (const float*)d_in[21];
    const float* eb1      = (const float*)d_in[22];
    const float* ew2      = (const float*)d_in[23];
    const float* eb2      = (const float*)d_in[24];
    const int* node_type  = (const int*)d_in[25];
    const int* edge_type  = (const int*)d_in[26];
    const int* edge_index = (const int*)d_in[27];
    const int* edit_mask  = (const int*)d_in[28];
    const int* node_batch = (const int*)d_in[29];
    const int* t_graph    = (const int*)d_in[30];
    const int* esrc = edge_index;
    const int* edst = edge_index + NE;

    char* wsb = (char*)d_ws;
    size_t off = 0;
    auto take = [&](size_t bytes) -> char* {
        char* r = wsb + off;
        off += (bytes + 255) & ~(size_t)255;
        return r;
    };
    float* tvec = (float*)take((size_t)NBATCH*H*4);
    float* x    = (float*)take((size_t)NN*H*4);
    u16*   xb   = (u16*)  take((size_t)NPAD*H*2);
    float* Q    = (float*)take((size_t)NN*H*4);
    u8*    Kb   = (u8*)   take((size_t)NN*RP);
    u8*    Vb   = (u8*)   take((size_t)NN*RP);
    float* XR   = (float*)take((size_t)NN*H*4);
    u8*    xs1  = (u8*)   take((size_t)NN*RP);
    u8*    xd1  = (u8*)   take((size_t)NN*RP);
    float* etab = (float*)take((size_t)NL*64*RP*4);
    float* ctab = (float*)take((size_t)64*RP*4);
    u16*   wt   = (u16*)  take((size_t)18*HH*2);
    int* cnt    = (int*)  take((size_t)(NN+1)*4);
    int* offa   = (int*)  take((size_t)(NN+1)*4);
    int* cur    = (int*)  take((size_t)(NN+1)*4);
    int* ssrc   = (int*)  take((size_t)NE*4);
    int* seix   = (int*)  take((size_t)NE*4);

    if(ws_size < off){
        k_sentinel<<<1,1,0,stream>>>((float*)d_out, 10000.f + (float)(ws_size >> 20));
        return;
    }

    k_transpose<<<dim3(18, 8), 256, 0, stream>>>(wq, wk, wv, wskip, ew1, wt);
    k_tvec<<<NBATCH, H, 0, stream>>>(t_graph, time_w1, time_b1, time_w2, time_b2, tvec);
    k_init_x<<<(NN*H + 255)/256, 256, 0, stream>>>(node_emb, mask_emb, tvec, node_type,
                                                   edit_mask, node_batch, x, xb);
    k_zero_i<<<(NN + 255)/256, 256, 0, stream>>>(cnt, NN);
    k_count<<<NE/256, 256, 0, stream>>>(edst, cnt);
    k_scan<<<1, 1024, 0, stream>>>(cnt, offa, cur);
    k_scatter<<<NE/256, 256, 0, stream>>>(esrc, edst, edge_type, node_batch, cur, ssrc, seix);
    k_etab<<<NL*64, H, 0, stream>>>(edge_emb, tvec, we, etab);
    k_ctab<<<64, H, 0, stream>>>(edge_emb, tvec, ew1, eb1, ctab);

    for(int l = 0; l < NL; l++){
        GemmP P;
        P.wt[0] = wt + (size_t)(0  + l)*HH;  P.bias[0] = bq   + (size_t)l*H;  P.out[0] = Q;  P.obf[0] = 0;
        P.wt[1] = wt + (size_t)(4  + l)*HH;  P.bias[1] = bk   + (size_t)l*H;  P.out[1] = Kb; P.obf[1] = 2;
        P.wt[2] = wt + (size_t)(8  + l)*HH;  P.bias[2] = bv   + (size_t)l*H;  P.out[2] = Vb; P.obf[2] = 2;
        P.wt[3] = wt + (size_t)(12 + l)*HH;  P.bias[3] = bskip+ (size_t)l*H;  P.out[3] = XR; P.obf[3] = 0;
        k_gemm<<<dim3(63, 12), 256, 0, stream>>>(xb, P);
        k_attn<<<NN/4, 256, 0, stream>>>(Q, Kb, Vb, XR, etab + (size_t)l*64*RP, offa, ssrc, seix,
                                         wbeta + (size_t)l*3*H, ln_g + (size_t)l*H,
                                         ln_b + (size_t)l*H, x, xb);
    }
    {
        GemmP P;
        P.wt[0] = wt + (size_t)16*HH; P.bias[0] = nullptr; P.out[0] = xs1; P.obf[0] = 2;
        P.wt[1] = wt + (size_t)17*HH; P.bias[1] = nullptr; P.out[1] = xd1; P.obf[1] = 2;
        P.wt[2] = P.wt[0]; P.bias[2] = nullptr; P.out[2] = xs1; P.obf[2] = 2;
        P.wt[3] = P.wt[0]; P.bias[3] = nullptr; P.out[3] = xs1; P.obf[3] = 2;
        k_gemm<<<dim3(63, 6), 256, 0, stream>>>(xb, P);
    }
    k_nodeout<<<NN/8, 256, 0, stream>>>(x, now, nob, (float*)d_out);
    k_edgemlp<<<NE/(4*EML), 256, 0, stream>>>(esrc, edst, edge_type, node_batch, xs1, xd1, ctab,
                                              ew2, eb2, (float*)d_out + (size_t)NN*32);
}